// Round 4
// baseline (298.112 us; speedup 1.0000x reference)
//
#include <hip/hip_runtime.h>
#include <stdint.h>

#define HIDDEN 1024
#define MROWS  32768
#define NPROTO 9
#define ZOFF   (MROWS * NPROTO)   // 294912 floats of logits, then z
#define BM     64
#define NT     32                  // K-steps of 32 (K=1024)

typedef __bf16 bf16x8 __attribute__((ext_vector_type(8)));
typedef float  f32x4  __attribute__((ext_vector_type(4)));

__device__ __forceinline__ unsigned short f2bf(float f) {
    unsigned u = __float_as_uint(f);
    u += 0x7fffu + ((u >> 16) & 1u);   // round-to-nearest-even
    return (unsigned short)(u >> 16);
}

// ---------------- prep: h (f32) -> bf16 ----------------
__global__ void k_conv_h(const float* __restrict__ src, unsigned short* __restrict__ dst, int n8) {
    int i0 = blockIdx.x * blockDim.x + threadIdx.x;
    int stride = gridDim.x * blockDim.x;
    for (int i = i0; i < n8; i += stride) {
        const float4* p = (const float4*)(src + (size_t)i * 8);
        float4 a = p[0], b = p[1];
        union { unsigned short us[8]; uint4 v; } o;
        o.us[0] = f2bf(a.x); o.us[1] = f2bf(a.y); o.us[2] = f2bf(a.z); o.us[3] = f2bf(a.w);
        o.us[4] = f2bf(b.x); o.us[5] = f2bf(b.y); o.us[6] = f2bf(b.z); o.us[7] = f2bf(b.w);
        *(uint4*)(dst + (size_t)i * 8) = o.v;
    }
}

// ---------------- prep: W*mask -> bf16 ----------------
__global__ void k_conv_w(const float* __restrict__ w, const float* __restrict__ m,
                         unsigned short* __restrict__ dst, int n8) {
    int i0 = blockIdx.x * blockDim.x + threadIdx.x;
    int stride = gridDim.x * blockDim.x;
    for (int i = i0; i < n8; i += stride) {
        const float4* pw = (const float4*)(w + (size_t)i * 8);
        const float4* pm = (const float4*)(m + (size_t)i * 8);
        float4 a = pw[0], b = pw[1], c = pm[0], d = pm[1];
        union { unsigned short us[8]; uint4 v; } o;
        o.us[0] = f2bf(a.x * c.x); o.us[1] = f2bf(a.y * c.y);
        o.us[2] = f2bf(a.z * c.z); o.us[3] = f2bf(a.w * c.w);
        o.us[4] = f2bf(b.x * d.x); o.us[5] = f2bf(b.y * d.y);
        o.us[6] = f2bf(b.z * d.z); o.us[7] = f2bf(b.w * d.w);
        *(uint4*)(dst + (size_t)i * 8) = o.v;
    }
}

// ---------------- prep: l2-normalized prototypes (first 9 rows) ----------------
__global__ void k_proto(const float* __restrict__ proto, float* __restrict__ pn) {
    __shared__ float red[4];
    int t = threadIdx.x, k = blockIdx.x;
    float4 v = *(const float4*)(proto + (size_t)k * HIDDEN + t * 4);
    float ss = v.x * v.x + v.y * v.y + v.z * v.z + v.w * v.w;
    #pragma unroll
    for (int m = 1; m < 64; m <<= 1) ss += __shfl_xor(ss, m);
    if ((t & 63) == 0) red[t >> 6] = ss;
    __syncthreads();
    ss = red[0] + red[1] + red[2] + red[3];
    float inv = 1.0f / fmaxf(sqrtf(ss), 1e-12f);
    float4 o; o.x = v.x * inv; o.y = v.y * inv; o.z = v.z * inv; o.w = v.w * inv;
    *(float4*)(pn + (size_t)k * HIDDEN + t * 4) = o;
}

// ---------------- fused GEMM + LayerNorm + l2norm + logits ----------------
// BM=64, BN=1024 (full rows), 8 waves; wave w owns 64 rows x cols [w*128, w*128+128).
// K-loop is LDS-FREE and BARRIER-FREE: A (4KB/step, L1-hot, 8x-shared) and B
// (per-wave-private rows, L2-resident 2MB) are loaded straight to registers,
// register double-buffered; all load offsets are compile-time immediates.
__global__ __launch_bounds__(512, 2) void k_gemm_ln(const unsigned short* __restrict__ A,
                                                    const unsigned short* __restrict__ B,
                                                    const float* __restrict__ gamma,
                                                    const float* __restrict__ beta,
                                                    const float* __restrict__ pn,
                                                    float* __restrict__ z,
                                                    float* __restrict__ logits) {
    __shared__ char smem[61952];   // epilogue only
    const int tid = threadIdx.x;
    const int wid = tid >> 6, lane = tid & 63;
    const int fr = lane & 15, kq = lane >> 4;
    const int bm0 = (int)blockIdx.x * BM;

    const unsigned short* ap[4];
    const unsigned short* bp[8];
    #pragma unroll
    for (int i = 0; i < 4; i++) ap[i] = A + (size_t)(bm0 + i * 16 + fr) * HIDDEN + kq * 8;
    #pragma unroll
    for (int j = 0; j < 8; j++) bp[j] = B + (size_t)(wid * 128 + j * 16 + fr) * HIDDEN + kq * 8;

    f32x4 acc[4][8] = {};
    bf16x8 a0[4], a1[4], b0[8], b1[8];

    auto loadA = [&](bf16x8* d, int t) {
        #pragma unroll
        for (int i = 0; i < 4; i++) d[i] = *(const bf16x8*)(ap[i] + t * 32);
    };
    auto loadB = [&](bf16x8* d, int t) {
        #pragma unroll
        for (int j = 0; j < 8; j++) d[j] = *(const bf16x8*)(bp[j] + t * 32);
    };
    auto mm = [&](const bf16x8* a, const bf16x8* b) {
        #pragma unroll
        for (int i = 0; i < 4; i++)
            #pragma unroll
            for (int j = 0; j < 8; j++)
                acc[i][j] = __builtin_amdgcn_mfma_f32_16x16x32_bf16(a[i], b[j], acc[i][j], 0, 0, 0);
    };

    loadA(a0, 0); loadB(b0, 0);
    #pragma unroll
    for (int tt = 0; tt < 16; ++tt) {
        const int t1 = 2 * tt + 1;
        const int t2 = (2 * tt + 2 < NT) ? 2 * tt + 2 : 0;   // last prefetch is a dummy
        loadA(a1, t1); loadB(b1, t1);
        mm(a0, b0);
        loadA(a0, t2); loadB(b0, t2);
        mm(a1, b1);
    }

    // ---- epilogue: LN + l2norm + logits (same as verified R3 epilogue) ----
    float* red_s     = (float*)smem;              // [8][64]
    float* red_sq    = (float*)(smem + 2048);     // [8][64]
    float* mu_lds    = (float*)(smem + 4096);     // [64]
    float* rs_lds    = (float*)(smem + 4352);     // [64]
    float* proto_lds = (float*)(smem + 4608);     // [9][1024] = 36864B
    float* part_lds  = (float*)(smem + 41472);    // [64][8][10] = 20480B

    // stage normalized protos (36 KB)
    #pragma unroll
    for (int i2 = 0; i2 < 5; i2++) {
        int idx = i2 * 512 + tid;
        if (idx < NPROTO * HIDDEN / 4) ((float4*)proto_lds)[idx] = ((const float4*)pn)[idx];
    }

    // per-(wave,row) s/sq partials over this wave's 128 cols
    #pragma unroll
    for (int i = 0; i < 4; i++) {
        #pragma unroll
        for (int r = 0; r < 4; r++) {
            float s = 0.f, sq = 0.f;
            #pragma unroll
            for (int j = 0; j < 8; j++) { float v = acc[i][j][r]; s += v; sq += v * v; }
            #pragma unroll
            for (int m = 1; m < 16; m <<= 1) { s += __shfl_xor(s, m); sq += __shfl_xor(sq, m); }
            if (fr == 0) {
                int row = i * 16 + kq * 4 + r;
                red_s[wid * 64 + row] = s;
                red_sq[wid * 64 + row] = sq;
            }
        }
    }
    __syncthreads();

    if (tid < 64) {
        float s = 0.f, sq = 0.f;
        #pragma unroll
        for (int w = 0; w < 8; w++) { s += red_s[w * 64 + tid]; sq += red_sq[w * 64 + tid]; }
        float mu = s * (1.0f / 1024.0f);
        float var = sq * (1.0f / 1024.0f) - mu * mu;
        mu_lds[tid] = mu;
        rs_lds[tid] = rsqrtf(var + 1e-5f);
    }
    __syncthreads();

    // gamma/beta for this lane's 8 columns
    float g[8], b[8];
    #pragma unroll
    for (int j = 0; j < 8; j++) {
        int col = wid * 128 + j * 16 + fr;
        g[j] = gamma[col];
        b[j] = beta[col];
    }

    // LN transform in-place + write z
    #pragma unroll
    for (int i = 0; i < 4; i++) {
        #pragma unroll
        for (int r = 0; r < 4; r++) {
            int row = i * 16 + kq * 4 + r;
            float mu = mu_lds[row], rs = rs_lds[row];
            float* zr = z + (size_t)(bm0 + row) * HIDDEN + wid * 128;
            #pragma unroll
            for (int j = 0; j < 8; j++) {
                float v = (acc[i][j][r] - mu) * rs * g[j] + b[j];
                acc[i][j][r] = v;
                zr[j * 16 + fr] = v;
            }
        }
    }

    // ss partials per row
    #pragma unroll
    for (int i = 0; i < 4; i++) {
        #pragma unroll
        for (int r = 0; r < 4; r++) {
            float ss = 0.f;
            #pragma unroll
            for (int j = 0; j < 8; j++) { float v = acc[i][j][r]; ss += v * v; }
            #pragma unroll
            for (int m = 1; m < 16; m <<= 1) ss += __shfl_xor(ss, m);
            if (fr == 0) {
                int row = i * 16 + kq * 4 + r;
                part_lds[(row * 8 + wid) * 10 + 9] = ss;
            }
        }
    }
    // proto-dot partials per row
    for (int k = 0; k < NPROTO; k++) {
        float p[8];
        #pragma unroll
        for (int j = 0; j < 8; j++) p[j] = proto_lds[k * HIDDEN + wid * 128 + j * 16 + fr];
        #pragma unroll
        for (int i = 0; i < 4; i++) {
            #pragma unroll
            for (int r = 0; r < 4; r++) {
                float d = 0.f;
                #pragma unroll
                for (int j = 0; j < 8; j++) d += acc[i][j][r] * p[j];
                #pragma unroll
                for (int m = 1; m < 16; m <<= 1) d += __shfl_xor(d, m);
                if (fr == 0) {
                    int row = i * 16 + kq * 4 + r;
                    part_lds[(row * 8 + wid) * 10 + k] = d;
                }
            }
        }
    }
    __syncthreads();

    if (tid < 64) {
        int row = tid;
        float dot[NPROTO];
        #pragma unroll
        for (int k = 0; k < NPROTO; k++) dot[k] = 0.f;
        float ss = 0.f;
        #pragma unroll
        for (int w = 0; w < 8; w++) {
            const float* pl = &part_lds[(row * 8 + w) * 10];
            #pragma unroll
            for (int k = 0; k < NPROTO; k++) dot[k] += pl[k];
            ss += pl[9];
        }
        float inv = 1.0f / (fmaxf(sqrtf(ss), 1e-12f) * 0.07f);
        float* lr = logits + (size_t)(bm0 + row) * NPROTO;
        #pragma unroll
        for (int k = 0; k < NPROTO; k++) lr[k] = dot[k] * inv;
    }
}

extern "C" void kernel_launch(void* const* d_in, const int* in_sizes, int n_in,
                              void* d_out, int out_size, void* d_ws, size_t ws_size,
                              hipStream_t stream) {
    const float* h     = (const float*)d_in[0];
    const float* w     = (const float*)d_in[1];
    const float* mask  = (const float*)d_in[2];
    const float* gamma = (const float*)d_in[3];
    const float* beta  = (const float*)d_in[4];
    const float* proto = (const float*)d_in[5];
    float* out    = (float*)d_out;
    float* logits = out;                       // 32768*9 floats
    float* z      = out + (size_t)ZOFF;        // 32768*1024 floats

    char* ws = (char*)d_ws;
    unsigned short* hb = (unsigned short*)ws;                        // 64 MB bf16 h
    unsigned short* wm = (unsigned short*)(ws + 67108864);           // 2 MB bf16 W*mask
    float*          pn = (float*)(ws + 67108864 + 2097152);          // 36 KB normalized protos

    k_conv_h<<<4096, 256, 0, stream>>>(h, hb, MROWS * HIDDEN / 8);
    k_conv_w<<<512, 256, 0, stream>>>(w, mask, wm, HIDDEN * HIDDEN / 8);
    k_proto<<<NPROTO, 256, 0, stream>>>(proto, pn);
    k_gemm_ln<<<MROWS / BM, 512, 0, stream>>>(hb, wm, gamma, beta, pn, z, logits);
}

// Round 5
// 201.698 us; speedup vs baseline: 1.4780x; 1.4780x over previous
//
#include <hip/hip_runtime.h>
#include <stdint.h>

#define HIDDEN 1024
#define MROWS  32768
#define NPROTO 9
#define ZOFF   (MROWS * NPROTO)   // 294912 floats of logits, then z

typedef __bf16 bf16x8 __attribute__((ext_vector_type(8)));
typedef float  f32x4  __attribute__((ext_vector_type(4)));

__device__ __forceinline__ unsigned short f2bf(float f) {
    unsigned u = __float_as_uint(f);
    u += 0x7fffu + ((u >> 16) & 1u);   // round-to-nearest-even
    return (unsigned short)(u >> 16);
}
__device__ __forceinline__ float bf2f(unsigned short u) {
    return __uint_as_float(((unsigned)u) << 16);
}

// ---------------- prep: W*mask -> bf16 ----------------
__global__ void k_conv_w(const float* __restrict__ w, const float* __restrict__ m,
                         unsigned short* __restrict__ dst, int n8) {
    int i0 = blockIdx.x * blockDim.x + threadIdx.x;
    int stride = gridDim.x * blockDim.x;
    for (int i = i0; i < n8; i += stride) {
        const float4* pw = (const float4*)(w + (size_t)i * 8);
        const float4* pm = (const float4*)(m + (size_t)i * 8);
        float4 a = pw[0], b = pw[1], c = pm[0], d = pm[1];
        union { unsigned short us[8]; uint4 v; } o;
        o.us[0] = f2bf(a.x * c.x); o.us[1] = f2bf(a.y * c.y);
        o.us[2] = f2bf(a.z * c.z); o.us[3] = f2bf(a.w * c.w);
        o.us[4] = f2bf(b.x * d.x); o.us[5] = f2bf(b.y * d.y);
        o.us[6] = f2bf(b.z * d.z); o.us[7] = f2bf(b.w * d.w);
        *(uint4*)(dst + (size_t)i * 8) = o.v;
    }
}

// ---------------- prep: l2-normalized prototypes (first 9 rows) ----------------
__global__ void k_proto(const float* __restrict__ proto, float* __restrict__ pn) {
    __shared__ float red[4];
    int t = threadIdx.x, k = blockIdx.x;
    float4 v = *(const float4*)(proto + (size_t)k * HIDDEN + t * 4);
    float ss = v.x * v.x + v.y * v.y + v.z * v.z + v.w * v.w;
    #pragma unroll
    for (int m = 1; m < 64; m <<= 1) ss += __shfl_xor(ss, m);
    if ((t & 63) == 0) red[t >> 6] = ss;
    __syncthreads();
    ss = red[0] + red[1] + red[2] + red[3];
    float inv = 1.0f / fmaxf(sqrtf(ss), 1e-12f);
    float4 o; o.x = v.x * inv; o.y = v.y * inv; o.z = v.z * inv; o.w = v.w * inv;
    *(float4*)(pn + (size_t)k * HIDDEN + t * 4) = o;
}

// ---------------- main GEMM: zp[m][o] = bf16( sum_d h[m][d] * wm[o][d] ) ----------------
// R2-verified 128x128/BK=32 structure. Changes vs R2:
//  * XCD swizzle: the 8 n-tiles of an A-panel land on one XCD (panel HBM-fetched once).
//  * A staged from f32 h directly (reg-load early -> cvt+ds_write late; T14 split).
//  * Output z_pre written bf16.
__global__ __launch_bounds__(256, 2) void k_gemm(const float* __restrict__ H,
                                                 const unsigned short* __restrict__ B,
                                                 unsigned short* __restrict__ ZP) {
    __shared__ unsigned short As[2][128 * 32];
    __shared__ unsigned short Bs[2][128 * 32];
    const int tid = threadIdx.x;
    const int wid = tid >> 6, lane = tid & 63;
    const int hw = (int)blockIdx.x;
    const int xcd = hw & 7, nblk = (hw >> 3) & 7, mloc = hw >> 6;
    const int bm0 = (xcd * 32 + mloc) * 128;
    const int bn0 = nblk * 128;
    const int wr = wid >> 1, wc = wid & 1;
    const int fr = lane & 15, kq = lane >> 4;

    // A reg-staging addressing: 256 threads cover 128 rows x 32 k (2 thr/row)
    const int arow = tid >> 1, ahalf = tid & 1;
    const float* ha = H + (size_t)(bm0 + arow) * HIDDEN + ahalf * 16;

    f32x4 acc[4][4] = {};

    auto loadA = [&](float4* f, int k0) {
        const float4* p = (const float4*)(ha + k0);
        #pragma unroll
        for (int q = 0; q < 4; q++) f[q] = p[q];
    };
    auto writeA = [&](int buf, const float4* f) {
        union { unsigned short us[16]; uint4 v[2]; } o;
        #pragma unroll
        for (int q = 0; q < 4; q++) {
            o.us[q * 4 + 0] = f2bf(f[q].x); o.us[q * 4 + 1] = f2bf(f[q].y);
            o.us[q * 4 + 2] = f2bf(f[q].z); o.us[q * 4 + 3] = f2bf(f[q].w);
        }
        uint4* dst = (uint4*)&As[buf][arow * 32 + ahalf * 16];
        dst[0] = o.v[0];
        dst[1] = o.v[1];
    };
    auto stageB = [&](int buf, int k0) {
        #pragma unroll
        for (int is = 0; is < 2; ++is) {
            int c = is * 256 + tid;
            int row = c >> 2, seg = c & 3;
            const unsigned short* gb = B + (size_t)(bn0 + row) * HIDDEN + k0 + seg * 8;
            void* lb = (void*)((char*)&Bs[buf][0] + (size_t)(is * 256 + wid * 64) * 16);
            __builtin_amdgcn_global_load_lds((const __attribute__((address_space(1))) void*)gb,
                                             (__attribute__((address_space(3))) void*)lb, 16, 0, 0);
        }
    };
    auto compute = [&](int buf) {
        bf16x8 av[4], bv[4];
        #pragma unroll
        for (int i = 0; i < 4; i++)
            av[i] = *(const bf16x8*)&As[buf][(wr * 64 + i * 16 + fr) * 32 + kq * 8];
        #pragma unroll
        for (int j = 0; j < 4; j++)
            bv[j] = *(const bf16x8*)&Bs[buf][(wc * 64 + j * 16 + fr) * 32 + kq * 8];
        #pragma unroll
        for (int i = 0; i < 4; i++)
            #pragma unroll
            for (int j = 0; j < 4; j++)
                acc[i][j] = __builtin_amdgcn_mfma_f32_16x16x32_bf16(av[i], bv[j], acc[i][j], 0, 0, 0);
    };

    float4 af[4];
    loadA(af, 0);
    stageB(0, 0);
    writeA(0, af);
    __syncthreads();
    int cur = 0;
    for (int t = 1; t < 32; t++) {
        float4 an[4];
        loadA(an, t * 32);        // issue next A f32 loads (latency hides under compute)
        stageB(cur ^ 1, t * 32);  // async B global->LDS
        compute(cur);
        writeA(cur ^ 1, an);      // cvt + ds_write after compute
        __syncthreads();
        cur ^= 1;
    }
    compute(cur);

    #pragma unroll
    for (int i = 0; i < 4; i++) {
        #pragma unroll
        for (int j = 0; j < 4; j++) {
            int col = bn0 + wc * 64 + j * 16 + fr;
            int rowb = bm0 + wr * 64 + i * 16 + kq * 4;
            #pragma unroll
            for (int r = 0; r < 4; r++)
                ZP[(size_t)(rowb + r) * HIDDEN + col] = f2bf(acc[i][j][r]);
        }
    }
}

// ---------------- LN + l2norm + prototype logits (bf16 z_pre in, f32 z out) ----------------
// One WAVE per row, no barriers in the row loop (R2-verified structure).
__global__ __launch_bounds__(256) void k_ln(const unsigned short* __restrict__ zp,
                                            float* __restrict__ z, float* __restrict__ logits,
                                            const float* __restrict__ gamma, const float* __restrict__ beta,
                                            const float* __restrict__ pn, int waves_total) {
    __shared__ float sp[NPROTO * HIDDEN];
    const int tid = threadIdx.x, wid = tid >> 6, lane = tid & 63;
    #pragma unroll
    for (int i = 0; i < NPROTO * HIDDEN / 4 / 256; i++) {
        int idx = (i * 256 + tid) * 4;
        *(float4*)&sp[idx] = *(const float4*)&pn[idx];
    }
    __syncthreads();

    float4 g4[4], b4[4];
    #pragma unroll
    for (int c = 0; c < 4; c++) {
        g4[c] = *(const float4*)(gamma + lane * 4 + 256 * c);
        b4[c] = *(const float4*)(beta  + lane * 4 + 256 * c);
    }

    const float inv_n = 1.0f / 1024.0f;
    int gw = blockIdx.x * 4 + wid;
    for (int row = gw; row < MROWS; row += waves_total) {
        const unsigned short* zr = zp + (size_t)row * HIDDEN;
        float4 v[4];
        #pragma unroll
        for (int c = 0; c < 4; c++) {
            ushort4 u = *(const ushort4*)(zr + lane * 4 + 256 * c);
            v[c].x = bf2f(u.x); v[c].y = bf2f(u.y); v[c].z = bf2f(u.z); v[c].w = bf2f(u.w);
        }

        float s = 0.f, sq = 0.f;
        #pragma unroll
        for (int c = 0; c < 4; c++) {
            s  += v[c].x + v[c].y + v[c].z + v[c].w;
            sq += v[c].x * v[c].x + v[c].y * v[c].y + v[c].z * v[c].z + v[c].w * v[c].w;
        }
        #pragma unroll
        for (int m = 1; m < 64; m <<= 1) { s += __shfl_xor(s, m); sq += __shfl_xor(sq, m); }

        float mu  = s * inv_n;
        float var = sq * inv_n - mu * mu;
        float rs  = rsqrtf(var + 1e-5f);

        float* zo = z + (size_t)row * HIDDEN;
        #pragma unroll
        for (int c = 0; c < 4; c++) {
            v[c].x = (v[c].x - mu) * rs * g4[c].x + b4[c].x;
            v[c].y = (v[c].y - mu) * rs * g4[c].y + b4[c].y;
            v[c].z = (v[c].z - mu) * rs * g4[c].z + b4[c].z;
            v[c].w = (v[c].w - mu) * rs * g4[c].w + b4[c].w;
            *(float4*)(zo + lane * 4 + 256 * c) = v[c];
        }

        float part[10];
        #pragma unroll
        for (int k = 0; k < 10; k++) part[k] = 0.f;
        #pragma unroll
        for (int c = 0; c < 4; c++) {
            part[9] += v[c].x * v[c].x + v[c].y * v[c].y + v[c].z * v[c].z + v[c].w * v[c].w;
            #pragma unroll
            for (int k = 0; k < 9; k++) {
                float4 p = *(const float4*)&sp[k * HIDDEN + lane * 4 + 256 * c];
                part[k] += v[c].x * p.x + v[c].y * p.y + v[c].z * p.z + v[c].w * p.w;
            }
        }
        #pragma unroll
        for (int m = 1; m < 64; m <<= 1) {
            #pragma unroll
            for (int k = 0; k < 10; k++) part[k] += __shfl_xor(part[k], m);
        }
        if (lane == 0) {
            float inv = 1.0f / (fmaxf(sqrtf(part[9]), 1e-12f) * 0.07f);
            #pragma unroll
            for (int k = 0; k < 9; k++) logits[(size_t)row * NPROTO + k] = part[k] * inv;
        }
    }
}

extern "C" void kernel_launch(void* const* d_in, const int* in_sizes, int n_in,
                              void* d_out, int out_size, void* d_ws, size_t ws_size,
                              hipStream_t stream) {
    const float* h     = (const float*)d_in[0];
    const float* w     = (const float*)d_in[1];
    const float* mask  = (const float*)d_in[2];
    const float* gamma = (const float*)d_in[3];
    const float* beta  = (const float*)d_in[4];
    const float* proto = (const float*)d_in[5];
    float* out    = (float*)d_out;
    float* logits = out;                       // 32768*9 floats
    float* z      = out + (size_t)ZOFF;        // 32768*1024 floats

    char* ws = (char*)d_ws;
    unsigned short* zp = (unsigned short*)ws;                        // 64 MB bf16 z_pre
    unsigned short* wm = (unsigned short*)(ws + 67108864);           // 2 MB bf16 W*mask
    float*          pn = (float*)(ws + 67108864 + 2097152);          // 36 KB normalized protos

    k_conv_w<<<512, 256, 0, stream>>>(w, mask, wm, HIDDEN * HIDDEN / 8);
    k_proto<<<NPROTO, 256, 0, stream>>>(proto, pn);
    k_gemm<<<2048, 256, 0, stream>>>(h, wm, zp);
    k_ln<<<2048, 256, 0, stream>>>(zp, z, logits, gamma, beta, pn, 2048 * 4);
}

// Round 6
// 179.042 us; speedup vs baseline: 1.6650x; 1.1265x over previous
//
#include <hip/hip_runtime.h>
#include <stdint.h>

#define HIDDEN 1024
#define MROWS  32768
#define NPROTO 9
#define ZOFF   (MROWS * NPROTO)   // 294912 floats of logits, then z

typedef __bf16 bf16x8 __attribute__((ext_vector_type(8)));
typedef float  f32x4  __attribute__((ext_vector_type(4)));

__device__ __forceinline__ unsigned short f2bf(float f) {
    unsigned u = __float_as_uint(f);
    u += 0x7fffu + ((u >> 16) & 1u);   // round-to-nearest-even
    return (unsigned short)(u >> 16);
}

// ---------------- prep: h (f32) -> bf16 ----------------
__global__ void k_conv_h(const float* __restrict__ src, unsigned short* __restrict__ dst, int n8) {
    int i0 = blockIdx.x * blockDim.x + threadIdx.x;
    int stride = gridDim.x * blockDim.x;
    for (int i = i0; i < n8; i += stride) {
        const float4* p = (const float4*)(src + (size_t)i * 8);
        float4 a = p[0], b = p[1];
        union { unsigned short us[8]; uint4 v; } o;
        o.us[0] = f2bf(a.x); o.us[1] = f2bf(a.y); o.us[2] = f2bf(a.z); o.us[3] = f2bf(a.w);
        o.us[4] = f2bf(b.x); o.us[5] = f2bf(b.y); o.us[6] = f2bf(b.z); o.us[7] = f2bf(b.w);
        *(uint4*)(dst + (size_t)i * 8) = o.v;
    }
}

// ---------------- prep: W*mask -> bf16 ----------------
__global__ void k_conv_w(const float* __restrict__ w, const float* __restrict__ m,
                         unsigned short* __restrict__ dst, int n8) {
    int i0 = blockIdx.x * blockDim.x + threadIdx.x;
    int stride = gridDim.x * blockDim.x;
    for (int i = i0; i < n8; i += stride) {
        const float4* pw = (const float4*)(w + (size_t)i * 8);
        const float4* pm = (const float4*)(m + (size_t)i * 8);
        float4 a = pw[0], b = pw[1], c = pm[0], d = pm[1];
        union { unsigned short us[8]; uint4 v; } o;
        o.us[0] = f2bf(a.x * c.x); o.us[1] = f2bf(a.y * c.y);
        o.us[2] = f2bf(a.z * c.z); o.us[3] = f2bf(a.w * c.w);
        o.us[4] = f2bf(b.x * d.x); o.us[5] = f2bf(b.y * d.y);
        o.us[6] = f2bf(b.z * d.z); o.us[7] = f2bf(b.w * d.w);
        *(uint4*)(dst + (size_t)i * 8) = o.v;
    }
}

// ---------------- prep: l2-normalized prototypes (first 9 rows) ----------------
__global__ void k_proto(const float* __restrict__ proto, float* __restrict__ pn) {
    __shared__ float red[4];
    int t = threadIdx.x, k = blockIdx.x;
    float4 v = *(const float4*)(proto + (size_t)k * HIDDEN + t * 4);
    float ss = v.x * v.x + v.y * v.y + v.z * v.z + v.w * v.w;
    #pragma unroll
    for (int m = 1; m < 64; m <<= 1) ss += __shfl_xor(ss, m);
    if ((t & 63) == 0) red[t >> 6] = ss;
    __syncthreads();
    ss = red[0] + red[1] + red[2] + red[3];
    float inv = 1.0f / fmaxf(sqrtf(ss), 1e-12f);
    float4 o; o.x = v.x * inv; o.y = v.y * inv; o.z = v.z * inv; o.w = v.w * inv;
    *(float4*)(pn + (size_t)k * HIDDEN + t * 4) = o;
}

// ---------------- main GEMM: z[m][o] = sum_d hb[m][d] * wm[o][d] ----------------
// R2-verified K-loop (global_load_lds for A and B, 2-phase dbuf, 128x128/BK=32)
// + XCD-aware block swizzle (verified at R5: FETCH 268 -> 82 MB).
// Swizzle: consecutive 64 block-ids on one XCD cover all 8 n-tiles of one
// m-panel -> A-panel fetched from HBM once per XCD-L2, not 8x.
__global__ __launch_bounds__(256, 2) void k_gemm(const unsigned short* __restrict__ A,
                                                 const unsigned short* __restrict__ B,
                                                 float* __restrict__ C) {
    __shared__ unsigned short As[2][128 * 32];
    __shared__ unsigned short Bs[2][128 * 32];
    const int tid = threadIdx.x;
    const int wid = tid >> 6, lane = tid & 63;
    const int hw = (int)blockIdx.x;
    const int xcd = hw & 7, nblk = (hw >> 3) & 7, mloc = hw >> 6;
    const int bm0 = (xcd * 32 + mloc) * 128;
    const int bn0 = nblk * 128;
    const int wr = wid >> 1, wc = wid & 1;
    const int fr = lane & 15, kq = lane >> 4;

    f32x4 acc[4][4] = {};

    auto stage = [&](int buf, int k0) {
        #pragma unroll
        for (int is = 0; is < 2; ++is) {
            int c = is * 256 + tid;
            int row = c >> 2, seg = c & 3;
            const unsigned short* ga = A + (size_t)(bm0 + row) * HIDDEN + k0 + seg * 8;
            void* la = (void*)((char*)&As[buf][0] + (size_t)(is * 256 + wid * 64) * 16);
            __builtin_amdgcn_global_load_lds((const __attribute__((address_space(1))) void*)ga,
                                             (__attribute__((address_space(3))) void*)la, 16, 0, 0);
            const unsigned short* gb = B + (size_t)(bn0 + row) * HIDDEN + k0 + seg * 8;
            void* lb = (void*)((char*)&Bs[buf][0] + (size_t)(is * 256 + wid * 64) * 16);
            __builtin_amdgcn_global_load_lds((const __attribute__((address_space(1))) void*)gb,
                                             (__attribute__((address_space(3))) void*)lb, 16, 0, 0);
        }
    };

    auto compute = [&](int buf) {
        bf16x8 av[4], bv[4];
        #pragma unroll
        for (int i = 0; i < 4; i++)
            av[i] = *(const bf16x8*)&As[buf][(wr * 64 + i * 16 + fr) * 32 + kq * 8];
        #pragma unroll
        for (int j = 0; j < 4; j++)
            bv[j] = *(const bf16x8*)&Bs[buf][(wc * 64 + j * 16 + fr) * 32 + kq * 8];
        #pragma unroll
        for (int i = 0; i < 4; i++)
            #pragma unroll
            for (int j = 0; j < 4; j++)
                acc[i][j] = __builtin_amdgcn_mfma_f32_16x16x32_bf16(av[i], bv[j], acc[i][j], 0, 0, 0);
    };

    stage(0, 0);
    __syncthreads();
    int cur = 0;
    for (int t = 1; t < 32; t++) {
        stage(cur ^ 1, t * 32);
        compute(cur);
        __syncthreads();
        cur ^= 1;
    }
    compute(cur);

    #pragma unroll
    for (int i = 0; i < 4; i++) {
        #pragma unroll
        for (int j = 0; j < 4; j++) {
            int col = bn0 + wc * 64 + j * 16 + fr;
            int rowb = bm0 + wr * 64 + i * 16 + kq * 4;
            #pragma unroll
            for (int r = 0; r < 4; r++)
                C[(size_t)(rowb + r) * HIDDEN + col] = acc[i][j][r];
        }
    }
}

// ---------------- LN + l2norm + prototype logits (in-place on z) ----------------
// One WAVE per row, no barriers in the row loop (R2-verified).
__global__ __launch_bounds__(256) void k_ln(float* __restrict__ z, float* __restrict__ logits,
                                            const float* __restrict__ gamma, const float* __restrict__ beta,
                                            const float* __restrict__ pn, int waves_total) {
    __shared__ float sp[NPROTO * HIDDEN];
    const int tid = threadIdx.x, wid = tid >> 6, lane = tid & 63;
    #pragma unroll
    for (int i = 0; i < NPROTO * HIDDEN / 4 / 256; i++) {
        int idx = (i * 256 + tid) * 4;
        *(float4*)&sp[idx] = *(const float4*)&pn[idx];
    }
    __syncthreads();

    float4 g4[4], b4[4];
    #pragma unroll
    for (int c = 0; c < 4; c++) {
        g4[c] = *(const float4*)(gamma + lane * 4 + 256 * c);
        b4[c] = *(const float4*)(beta  + lane * 4 + 256 * c);
    }

    const float inv_n = 1.0f / 1024.0f;
    int gw = blockIdx.x * 4 + wid;
    for (int row = gw; row < MROWS; row += waves_total) {
        float* zr = z + (size_t)row * HIDDEN;
        float4 v[4];
        #pragma unroll
        for (int c = 0; c < 4; c++) v[c] = *(const float4*)(zr + lane * 4 + 256 * c);

        float s = 0.f, sq = 0.f;
        #pragma unroll
        for (int c = 0; c < 4; c++) {
            s  += v[c].x + v[c].y + v[c].z + v[c].w;
            sq += v[c].x * v[c].x + v[c].y * v[c].y + v[c].z * v[c].z + v[c].w * v[c].w;
        }
        #pragma unroll
        for (int m = 1; m < 64; m <<= 1) { s += __shfl_xor(s, m); sq += __shfl_xor(sq, m); }

        float mu  = s * inv_n;
        float var = sq * inv_n - mu * mu;
        float rs  = rsqrtf(var + 1e-5f);

        #pragma unroll
        for (int c = 0; c < 4; c++) {
            v[c].x = (v[c].x - mu) * rs * g4[c].x + b4[c].x;
            v[c].y = (v[c].y - mu) * rs * g4[c].y + b4[c].y;
            v[c].z = (v[c].z - mu) * rs * g4[c].z + b4[c].z;
            v[c].w = (v[c].w - mu) * rs * g4[c].w + b4[c].w;
            *(float4*)(zr + lane * 4 + 256 * c) = v[c];
        }

        float part[10];
        #pragma unroll
        for (int k = 0; k < 10; k++) part[k] = 0.f;
        #pragma unroll
        for (int c = 0; c < 4; c++) {
            part[9] += v[c].x * v[c].x + v[c].y * v[c].y + v[c].z * v[c].z + v[c].w * v[c].w;
            #pragma unroll
            for (int k = 0; k < 9; k++) {
                float4 p = *(const float4*)&sp[k * HIDDEN + lane * 4 + 256 * c];
                part[k] += v[c].x * p.x + v[c].y * p.y + v[c].z * p.z + v[c].w * p.w;
            }
        }
        #pragma unroll
        for (int m = 1; m < 64; m <<= 1) {
            #pragma unroll
            for (int k = 0; k < 10; k++) part[k] += __shfl_xor(part[k], m);
        }
        if (lane == 0) {
            float inv = 1.0f / (fmaxf(sqrtf(part[9]), 1e-12f) * 0.07f);
            #pragma unroll
            for (int k = 0; k < 9; k++) logits[(size_t)row * NPROTO + k] = part[k] * inv;
        }
    }
}

extern "C" void kernel_launch(void* const* d_in, const int* in_sizes, int n_in,
                              void* d_out, int out_size, void* d_ws, size_t ws_size,
                              hipStream_t stream) {
    const float* h     = (const float*)d_in[0];
    const float* w     = (const float*)d_in[1];
    const float* mask  = (const float*)d_in[2];
    const float* gamma = (const float*)d_in[3];
    const float* beta  = (const float*)d_in[4];
    const float* proto = (const float*)d_in[5];
    float* out    = (float*)d_out;
    float* logits = out;                       // 32768*9 floats
    float* z      = out + (size_t)ZOFF;        // 32768*1024 floats

    char* ws = (char*)d_ws;
    unsigned short* hb = (unsigned short*)ws;                        // 64 MB bf16 h
    unsigned short* wm = (unsigned short*)(ws + 67108864);           // 2 MB bf16 W*mask
    float*          pn = (float*)(ws + 67108864 + 2097152);          // 36 KB normalized protos

    k_conv_h<<<4096, 256, 0, stream>>>(h, hb, MROWS * HIDDEN / 8);
    k_conv_w<<<512, 256, 0, stream>>>(w, mask, wm, HIDDEN * HIDDEN / 8);
    k_proto<<<NPROTO, 256, 0, stream>>>(proto, pn);
    k_gemm<<<2048, 256, 0, stream>>>(hb, wm, z);
    k_ln<<<2048, 256, 0, stream>>>(z, logits, gamma, beta, pn, 2048 * 4);
}